// Round 8
// baseline (908.602 us; speedup 1.0000x reference)
//
#include <hip/hip_runtime.h>
#include <hip/hip_bf16.h>
#include <cstdint>

#define B_   2
#define S_   2048
#define HID_ 3072
#define H_   16
#define KV_  8
#define D_   256
#define HD_  4096   // H_*D_
#define KVD_ 2048   // KV_*D_
#define QKS_ 8192   // merged qkv row stride

constexpr float EPS_   = 1e-6f;
constexpr float SCALE_ = 0.0625f;   // 256^-0.5

typedef unsigned short u16;
typedef __attribute__((ext_vector_type(8))) short bf16x8;
typedef __attribute__((ext_vector_type(4))) float f32x4;

__device__ inline float bf2f(u16 u) { return __uint_as_float(((unsigned int)u) << 16); }
__device__ inline u16 f2bf(float f) {
  unsigned int x = __float_as_uint(f);
  x += 0x7fffu + ((x >> 16) & 1u);   // RNE
  return (u16)(x >> 16);
}

// async global->LDS, 16B per lane; lds base must be wave-uniform, data lands at base + lane*16
__device__ inline void gll16(const u16* g, u16* l) {
  __builtin_amdgcn_global_load_lds((const __attribute__((address_space(1))) unsigned int*)g,
                                   (__attribute__((address_space(3))) unsigned int*)l,
                                   16, 0, 0);
}

// ---------------- elementwise cast f32 -> bf16 (n4 = n/4) ----------------
__global__ void cast_f32_bf16(const float* __restrict__ in, u16* __restrict__ out, int n4) {
  int i = blockIdx.x * blockDim.x + threadIdx.x;
  if (i < n4) {
    float4 v = ((const float4*)in)[i];
    ushort4 o;
    o.x = f2bf(v.x); o.y = f2bf(v.y); o.z = f2bf(v.z); o.w = f2bf(v.w);
    ((ushort4*)out)[i] = o;
  }
}

// ------------- transpose+cast: in[K][N] f32 -> out[N][K] bf16 -------------
__global__ void transpose_cast(const float* __restrict__ in, u16* __restrict__ out, int K, int N) {
  __shared__ __align__(16) float tile[64][65];
  int n0 = blockIdx.x * 64, k0 = blockIdx.y * 64;
  int t = threadIdx.x;
  int rr = t >> 4, cc = (t & 15) * 4;
  for (int i = 0; i < 4; i++) {
    float4 v = *(const float4*)(&in[(size_t)(k0 + rr + 16 * i) * N + n0 + cc]);
    tile[rr + 16 * i][cc + 0] = v.x; tile[rr + 16 * i][cc + 1] = v.y;
    tile[rr + 16 * i][cc + 2] = v.z; tile[rr + 16 * i][cc + 3] = v.w;
  }
  __syncthreads();
  for (int i = 0; i < 4; i++) {
    int orow = rr + 16 * i;  // n index
    ushort4 o;
    o.x = f2bf(tile[cc + 0][orow]); o.y = f2bf(tile[cc + 1][orow]);
    o.z = f2bf(tile[cc + 2][orow]); o.w = f2bf(tile[cc + 3][orow]);
    *(ushort4*)(&out[(size_t)(n0 + orow) * K + k0 + cc]) = o;
  }
}

// ----- bf16 transpose: in (xqkv V cols, stride 8192) -> out[b][2048 n][2048 s] -----
__global__ void transpose_v(const u16* __restrict__ in, u16* __restrict__ out) {
  __shared__ __align__(16) u16 tile[64][68];
  int n0 = blockIdx.x * 64, tk0 = blockIdx.y * 64;
  int b = tk0 >> 11, s0 = tk0 & (S_ - 1);
  int t = threadIdx.x;
  int rr = t >> 4, cc = (t & 15) * 4;
  for (int i = 0; i < 4; i++) {
    ushort4 v = *(const ushort4*)(&in[(size_t)(tk0 + rr + 16 * i) * QKS_ + n0 + cc]);
    tile[rr + 16 * i][cc + 0] = v.x; tile[rr + 16 * i][cc + 1] = v.y;
    tile[rr + 16 * i][cc + 2] = v.z; tile[rr + 16 * i][cc + 3] = v.w;
  }
  __syncthreads();
  for (int i = 0; i < 4; i++) {
    int orow = rr + 16 * i;  // n index
    ushort4 o;
    o.x = tile[cc + 0][orow]; o.y = tile[cc + 1][orow];
    o.z = tile[cc + 2][orow]; o.w = tile[cc + 3][orow];
    *(ushort4*)(&out[((size_t)b << 22) + (size_t)(n0 + orow) * S_ + s0 + cc]) = o;
  }
}

// ===== 256x256 8-wave GEMM, A via LDS + B direct global->reg: C = A*Bt^T =====
// v5: B fragments are per-wave private -> load straight from global (L1/L2-hot
// strips), removing B's LDS DMA-writes AND LDS reads: LDS traffic/tile drops
// 320KB -> 160KB (< MFMA time). Zero extra registers: B01 regs die after Q2
// and are reloaded for t+1 after Q3; B23 dies after Q4, reloaded after Q4.
// vmcnt choreography per tile (entering queue = [Ast(t+1):4][B01(t):4][B23(t):4]):
// vmcnt(4) before Q1 (retires Ast+B01), vmcnt(0) before barrier (retires B23).
// A free-runs as v4: one barrier/tile; A-reads retired (lgkm 0) pre-barrier;
// A-stage(t+2) into buf[cur] post-barrier; A0'(t+1) preread at tile end.
template <bool OUTF32>
__global__ __launch_bounds__(512, 2) void gemm256(const u16* __restrict__ A,
                                                  const u16* __restrict__ Bt,
                                                  void* __restrict__ Cv, int M, int N, int K) {
  __shared__ __align__(16) u16 As[2][16384];
  int t = threadIdx.x, lane = t & 63, wave = t >> 6;
  int quad = lane >> 4, l16 = lane & 15;
  int wm = wave >> 2, wn = wave & 3;

  // XCD-chunked bid swizzle (requires nwg % 8 == 0; 512 and 192 both qualify)
  int nwg = gridDim.x * gridDim.y;
  int bid = blockIdx.y * gridDim.x + blockIdx.x;
  int sbid = (bid & 7) * (nwg >> 3) + (bid >> 3);
  int bn = (sbid % gridDim.x) * 256;
  int bm = (sbid / gridDim.x) * 256;

  // A staging: one gll16 fills one 16x32 subtile (1KB); lane l -> row l>>2,
  // phys slot l&3 holding logical slot (l&3)^((l>>3)&3)
  int srow = lane >> 2;
  int scol8 = ((lane & 3) ^ ((lane >> 3) & 3)) * 8;
  const u16* ap = A + (size_t)(bm + srow) * K + scol8;

  auto stA = [&](int sr, int sc, int k0, int bufi) {
    gll16(ap + (size_t)(sr * 16) * K + k0 + sc * 32, &As[bufi][(sr * 2 + sc) * 512]);
  };
  auto stageTileA = [&](int kt, int bufi) {   // 4 gll16/wave = full 256x64 A tile
    int k0 = kt * 64;
    stA(wave * 2, 0, k0, bufi); stA(wave * 2, 1, k0, bufi);
    stA(wave * 2 + 1, 0, k0, bufi); stA(wave * 2 + 1, 1, k0, bufi);
  };

  // A frag read offset within a subtile (uniform banks: slot = quad ^ ((l16>>1)&3))
  int rsw = l16 * 32 + ((quad ^ ((l16 >> 1) & 3)) * 8);
  auto LDA = [&](int bufi, int i, int ks) {
    return *(const bf16x8*)(&As[bufi][((wm * 8 + i) * 2 + ks) * 512 + rsw]);
  };

  // B direct: frag (j,ks) @ tile kt2 = rows bn+wn*64+j*16+l16, cols kt2*64+ks*32+quad*8
  const u16* bq = Bt + (size_t)(bn + wn * 64 + l16) * K + quad * 8;
  auto GLB = [&](int j, int ks, int kt2) {
    return *(const bf16x8*)(bq + (size_t)(j * 16) * K + kt2 * 64 + ks * 32);
  };

  f32x4 acc[8][4] = {};
  int NT = K >> 6;

  bf16x8 A0[4][2], A1[4][2], B01[2][2], B23[2][2];

  // prologue: stage A tiles 0,1; load B(0); wait A(0); preread A0
  stageTileA(0, 0);
  stageTileA(1, 1);
#pragma unroll
  for (int j = 0; j < 2; j++) { B01[j][0] = GLB(j, 0, 0); B01[j][1] = GLB(j, 1, 0); }
#pragma unroll
  for (int j = 0; j < 2; j++) { B23[j][0] = GLB(j + 2, 0, 0); B23[j][1] = GLB(j + 2, 1, 0); }
  asm volatile("s_waitcnt vmcnt(12)" ::: "memory");   // A tile 0 landed
  __builtin_amdgcn_s_barrier();
  asm volatile("" ::: "memory");
#pragma unroll
  for (int i = 0; i < 4; i++) { A0[i][0] = LDA(0, i, 0); A0[i][1] = LDA(0, i, 1); }

#pragma unroll 1
  for (int kt = 0; kt < NT; kt++) {
    int cur = kt & 1, nxt = cur ^ 1;
    bool rd = (kt + 1) < NT;

    // 1: read A1 [cur]
#pragma unroll
    for (int i = 0; i < 4; i++) { A1[i][0] = LDA(cur, i + 4, 0); A1[i][1] = LDA(cur, i + 4, 1); }
    // 2: A0 preread done (A1 may fly); 3: B01(t) + own A-stage(t+1) landed
    asm volatile("s_waitcnt lgkmcnt(8)" ::: "memory");
    asm volatile("s_waitcnt vmcnt(4)" ::: "memory");
    // 4: Q1 = A0 x B01
    __builtin_amdgcn_s_setprio(1);
#pragma unroll
    for (int i = 0; i < 4; i++)
#pragma unroll
      for (int j = 0; j < 2; j++) {
        acc[i][j] = __builtin_amdgcn_mfma_f32_16x16x32_bf16(A0[i][0], B01[j][0], acc[i][j], 0, 0, 0);
        acc[i][j] = __builtin_amdgcn_mfma_f32_16x16x32_bf16(A0[i][1], B01[j][1], acc[i][j], 0, 0, 0);
      }
    __builtin_amdgcn_s_setprio(0);
    // 5: A1 done
    asm volatile("s_waitcnt lgkmcnt(0)" ::: "memory");
    // 6: Q2 = A1 x B01  (B01 regs dead after)
    __builtin_amdgcn_s_setprio(1);
#pragma unroll
    for (int i = 0; i < 4; i++)
#pragma unroll
      for (int j = 0; j < 2; j++) {
        acc[i + 4][j] = __builtin_amdgcn_mfma_f32_16x16x32_bf16(A1[i][0], B01[j][0], acc[i + 4][j], 0, 0, 0);
        acc[i + 4][j] = __builtin_amdgcn_mfma_f32_16x16x32_bf16(A1[i][1], B01[j][1], acc[i + 4][j], 0, 0, 0);
      }
    __builtin_amdgcn_s_setprio(0);
    // 7: B23(t) landed (queue empties); 8: single convergence point
    asm volatile("s_waitcnt vmcnt(0)" ::: "memory");
    __builtin_amdgcn_s_barrier();
    asm volatile("" ::: "memory");
    // 9: stage A(t+2) into buf[cur] (WAR-safe: all cur A-reads drained pre-barrier)
    if (kt + 2 < NT) stageTileA(kt + 2, cur);
    // 10: Q3 = A0 x B23  (A0 regs dead after)
    __builtin_amdgcn_s_setprio(1);
#pragma unroll
    for (int i = 0; i < 4; i++)
#pragma unroll
      for (int j = 0; j < 2; j++) {
        acc[i][j + 2] = __builtin_amdgcn_mfma_f32_16x16x32_bf16(A0[i][0], B23[j][0], acc[i][j + 2], 0, 0, 0);
        acc[i][j + 2] = __builtin_amdgcn_mfma_f32_16x16x32_bf16(A0[i][1], B23[j][1], acc[i][j + 2], 0, 0, 0);
      }
    __builtin_amdgcn_s_setprio(0);
    // 11: load B01'(t+1) into dead B01 regs
    if (rd) {
#pragma unroll
      for (int j = 0; j < 2; j++) { B01[j][0] = GLB(j, 0, kt + 1); B01[j][1] = GLB(j, 1, kt + 1); }
    }
    // 12: Q4 = A1 x B23  (A1, B23 regs dead after)
    __builtin_amdgcn_s_setprio(1);
#pragma unroll
    for (int i = 0; i < 4; i++)
#pragma unroll
      for (int j = 0; j < 2; j++) {
        acc[i + 4][j + 2] = __builtin_amdgcn_mfma_f32_16x16x32_bf16(A1[i][0], B23[j][0], acc[i + 4][j + 2], 0, 0, 0);
        acc[i + 4][j + 2] = __builtin_amdgcn_mfma_f32_16x16x32_bf16(A1[i][1], B23[j][1], acc[i + 4][j + 2], 0, 0, 0);
      }
    __builtin_amdgcn_s_setprio(0);
    // 13: load B23'(t+1) into dead B23 regs
    if (rd) {
#pragma unroll
      for (int j = 0; j < 2; j++) { B23[j][0] = GLB(j + 2, 0, kt + 1); B23[j][1] = GLB(j + 2, 1, kt + 1); }
    }
    // 14: preread A0'(t+1) from buf[nxt] (A-stage(t+1) landed: step 3 + barrier)
    if (rd) {
#pragma unroll
      for (int i = 0; i < 4; i++) { A0[i][0] = LDA(nxt, i, 0); A0[i][1] = LDA(nxt, i, 1); }
    }
  }

  // epilogue
#pragma unroll
  for (int i = 0; i < 8; i++)
#pragma unroll
    for (int j = 0; j < 4; j++)
#pragma unroll
      for (int r = 0; r < 4; r++) {
        int row = bm + wm * 128 + i * 16 + quad * 4 + r;
        int col = bn + wn * 64 + j * 16 + l16;
        float v = acc[i][j][r];
        if (OUTF32) ((float*)Cv)[(size_t)row * N + col] = v;
        else ((u16*)Cv)[(size_t)row * N + col] = f2bf(v);
      }
}

// ----- fused RMSNorm + RoPE, in place on bf16 [token][stride]; 1 wave/head -----
__global__ void rmsnorm_rope(u16* __restrict__ x, const float* __restrict__ w,
                             const float* __restrict__ fc, const float* __restrict__ fsn,
                             int nh, int stride, float outscale) {
  int token = blockIdx.x;
  int head = blockIdx.y * 4 + (threadIdx.x >> 6);
  if (head >= nh) return;
  int lane = threadIdx.x & 63;
  int s = token & (S_ - 1);
  u16* p = x + (size_t)token * stride + head * D_;
  float v0 = bf2f(p[lane]);
  float v1 = bf2f(p[lane + 64]);
  float v2 = bf2f(p[lane + 128]);
  float v3 = bf2f(p[lane + 192]);
  float ss = v0 * v0 + v1 * v1 + v2 * v2 + v3 * v3;
  for (int off = 32; off; off >>= 1) ss += __shfl_xor(ss, off, 64);
  float rs = rsqrtf(ss * (1.0f / D_) + EPS_);
  float n0 = v0 * rs * (1.0f + w[lane]);
  float n1 = v1 * rs * (1.0f + w[lane + 64]);
  float n2 = v2 * rs * (1.0f + w[lane + 128]);
  float n3 = v3 * rs * (1.0f + w[lane + 192]);
  float c0 = fc[s * 128 + lane], s0 = fsn[s * 128 + lane];
  float c1 = fc[s * 128 + lane + 64], s1 = fsn[s * 128 + lane + 64];
  p[lane]       = f2bf((n0 * c0 - n2 * s0) * outscale);
  p[lane + 128] = f2bf((n0 * s0 + n2 * c0) * outscale);
  p[lane + 64]  = f2bf((n1 * c1 - n3 * s1) * outscale);
  p[lane + 192] = f2bf((n1 * s1 + n3 * c1) * outscale);
}

// ---------------- flash attention, causal, GQA rep=2, D=256 ----------------
// v4 + merged-qkv strides: Q/K rows have stride 8192.
__global__ __launch_bounds__(256, 3) void flash_attn(const u16* __restrict__ Q,
                                                     const u16* __restrict__ Kb,
                                                     const u16* __restrict__ Vt,
                                                     u16* __restrict__ O) {
  __shared__ __align__(16) u16 Ks[2][8 * 1024];   // [buf][chunk c][key 0..31][slot-swz 32 d]
  __shared__ __align__(16) u16 Vs[8 * 1024];      // [d 0..255][slot-swz 32 k]
  int t = threadIdx.x, lane = t & 63, wave = t >> 6;
  int quad = lane >> 4, l16 = lane & 15;
  int h = blockIdx.y, b = blockIdx.z;
  int kvh = h >> 1;

  int swz = ((lane & 3) ^ ((lane >> 2) & 3)) * 8;        // staging-side d/k offset
  int rswz = (quad ^ (l16 & 3)) * 8;                     // read-side slot offset
  const u16* kst = Kb + (size_t)(b * S_ + (lane >> 2)) * QKS_ + kvh * D_ + wave * 64 + swz;
  const u16* vst = Vt + ((size_t)b << 22) + (size_t)(kvh * D_ + wave * 64 + (lane >> 2)) * S_ + swz;

  auto stageK = [&](int kt, int bufi) {
    u16* kdst = &Ks[bufi][wave * 2048];
    const u16* ksrc = kst + (size_t)(kt * 32) * QKS_;
#pragma unroll
    for (int c2 = 0; c2 < 2; c2++)
#pragma unroll
      for (int r = 0; r < 2; r++)
        gll16(ksrc + (size_t)(r * 16) * QKS_ + c2 * 32, kdst + c2 * 1024 + r * 512);
  };  // 4 gll16
  auto stageV = [&](int kt) {
    u16* vdst = &Vs[wave * 2048];
#pragma unroll
    for (int c = 0; c < 4; c++)
      gll16(vst + (size_t)(c * 16) * S_ + kt * 32, vdst + c * 512);
  };  // 4 gll16

#pragma unroll 1
  for (int half = 0; half < 2; half++) {
    // big q-tile first, then the paired small one: iters (64-2bx) + (2bx+2) = 66
    int qb = (half == 0) ? (31 - (int)blockIdx.x) * 64 : (int)blockIdx.x * 64;
    int qw = qb + wave * 16;

    bf16x8 qf[8];
    const u16* qp = Q + ((size_t)(b * S_) + qw + l16) * QKS_ + h * D_;
#pragma unroll
    for (int c = 0; c < 8; c++) qf[c] = *(const bf16x8*)(qp + c * 32 + quad * 8);

    f32x4 o_acc[16] = {};
    float m_s = -3e38f, l_s = 0.f;    // per-lane softmax state for row q = qw + l16

    int nkt = (qb + 64) >> 5;
    stageK(0, 0);
    stageV(0);
#pragma unroll 1
    for (int kt = 0; kt < nkt; kt++) {
      int cur = kt & 1;
      asm volatile("s_waitcnt vmcnt(4)" ::: "memory");
      __builtin_amdgcn_s_barrier();
      asm volatile("" ::: "memory");
      if (kt + 1 < nkt) stageK(kt + 1, cur ^ 1);

      // ---- QK (swapped): sc[key][q], q = l16 ----
      f32x4 sc0 = {}, sc1 = {};
#pragma unroll
      for (int c = 0; c < 8; c++) {
        bf16x8 k0 = *(const bf16x8*)(&Ks[cur][c * 1024 + l16 * 32 + rswz]);
        bf16x8 k1 = *(const bf16x8*)(&Ks[cur][c * 1024 + (l16 + 16) * 32 + rswz]);
        sc0 = __builtin_amdgcn_mfma_f32_16x16x32_bf16(k0, qf[c], sc0, 0, 0, 0);
        sc1 = __builtin_amdgcn_mfma_f32_16x16x32_bf16(k1, qf[c], sc1, 0, 0, 0);
      }

      // ---- lane-local online softmax (row q = qw + l16) ----
      int qg = qw + l16;
      int kbase = kt * 32 + quad * 4;
      float p0[4], p1[4];
      float mx = -1e30f;
#pragma unroll
      for (int r = 0; r < 4; r++) {
        p0[r] = (kbase + r <= qg) ? sc0[r] : -1e30f;
        p1[r] = (kbase + 16 + r <= qg) ? sc1[r] : -1e30f;
        mx = fmaxf(mx, fmaxf(p0[r], p1[r]));
      }
      mx = fmaxf(mx, __shfl_xor(mx, 16));
      mx = fmaxf(mx, __shfl_xor(mx, 32));
      float mn = fmaxf(m_s, mx);
      bool chg = mn > m_s;
      float rsum = 0.f;
#pragma unroll
      for (int r = 0; r < 4; r++) {
        p0[r] = __expf(p0[r] - mn);
        p1[r] = __expf(p1[r] - mn);
        rsum += p0[r] + p1[r];
      }
      if (__any((int)chg)) {
        float alpha = __expf(m_s - mn);
        float ar[4];
#pragma unroll
        for (int r = 0; r < 4; r++) ar[r] = __shfl(alpha, quad * 20 + r);
#pragma unroll
        for (int nt = 0; nt < 16; nt++)
#pragma unroll
          for (int r = 0; r < 4; r++) o_acc[nt][r] *= ar[r];
        l_s *= alpha;
      }
      m_s = mn;
      rsum += __shfl_xor(rsum, 16);
      rsum += __shfl_xor(rsum, 32);
      l_s += rsum;

      // ---- P: C-layout -> A-frag fully in-register (2-stage butterfly) ----
      unsigned int w_[4], x_[4], gl[4], gh[4], sn[4], rc[4];
      w_[0] = (unsigned)f2bf(p0[0]) | ((unsigned)f2bf(p0[1]) << 16);
      w_[1] = (unsigned)f2bf(p0[2]) | ((unsigned)f2bf(p0[3]) << 16);
      w_[2] = (unsigned)f2bf(p1[0]) | ((unsigned)f2bf(p1[1]) << 16);
      w_[3] = (unsigned)f2bf(p1[2]) | ((unsigned)f2bf(p1[3]) << 16);
#pragma unroll
      for (int i = 0; i < 4; i++) x_[i] = (unsigned)__shfl_xor((int)w_[i], 16);
      bool odd = (quad & 1) != 0;
      gl[0] = odd ? x_[0] : w_[0]; gl[1] = odd ? x_[1] : w_[1];
      gl[2] = odd ? w_[0] : x_[0]; gl[3] = odd ? w_[1] : x_[1];
      gh[0] = odd ? x_[2] : w_[2]; gh[1] = odd ? x_[3] : w_[3];
      gh[2] = odd ? w_[2] : x_[2]; gh[3] = odd ? w_[3] : x_[3];
#pragma unroll
      for (int i = 0; i < 4; i++) sn[i] = odd ? gl[i] : gh[i];
#pragma unroll
      for (int i = 0; i < 4; i++) rc[i] = (unsigned)__shfl_xor((int)sn[i], 32);
      union { unsigned int u[4]; bf16x8 v; } pfc;
#pragma unroll
      for (int i = 0; i < 4; i++)
        pfc.u[i] = (quad == 0) ? gl[i] : (quad == 3) ? gh[i] : rc[i];
      bf16x8 pf = pfc.v;

      if (kt + 1 < nkt) asm volatile("s_waitcnt vmcnt(4)" ::: "memory");
      else              asm volatile("s_waitcnt vmcnt(0)" ::: "memory");
      __builtin_amdgcn_s_barrier();
      asm volatile("" ::: "memory");

      // ---- PV ----
#pragma unroll
      for (int nt = 0; nt < 16; nt++) {
        bf16x8 vf = *(const bf16x8*)(&Vs[(nt * 16 + l16) * 32 + rswz]);
        o_acc[nt] = __builtin_amdgcn_mfma_f32_16x16x32_bf16(pf, vf, o_acc[nt], 0, 0, 0);
      }

      asm volatile("s_waitcnt lgkmcnt(0)" ::: "memory");
      __builtin_amdgcn_s_barrier();
      asm volatile("" ::: "memory");
      if (kt + 1 < nkt) stageV(kt + 1);
    }

    float invl = 1.0f / l_s;
    float inv_r[4];
#pragma unroll
    for (int r = 0; r < 4; r++) inv_r[r] = __shfl(invl, quad * 20 + r);
    for (int r = 0; r < 4; r++) {
      int qg2 = qw + quad * 4 + r;
      u16* op = O + ((size_t)(b * S_) + qg2) * HD_ + h * D_;
      for (int nt = 0; nt < 16; nt++) op[nt * 16 + l16] = f2bf(o_acc[nt][r] * inv_r[r]);
    }
  }
}

extern "C" void kernel_launch(void* const* d_in, const int* in_sizes, int n_in,
                              void* d_out, int out_size, void* d_ws, size_t ws_size,
                              hipStream_t stream) {
  const float* hs  = (const float*)d_in[0];
  const float* fc  = (const float*)d_in[1];
  const float* fsn = (const float*)d_in[2];
  // d_in[3] = mask: causal, replicated analytically
  const float* qw  = (const float*)d_in[4];
  const float* kw  = (const float*)d_in[5];
  const float* vw  = (const float*)d_in[6];
  const float* ow  = (const float*)d_in[7];
  const float* qnw = (const float*)d_in[8];
  const float* knw = (const float*)d_in[9];

  char* ws = (char*)d_ws;
  // layout (bytes):
  u16* x_bf   = (u16*)(ws + 0);          // 4096*3072*2 = 25165824 (dead after QKV GEMM)
  u16* vt     = (u16*)(ws + 0);          // 2*2048*2048*2 = 16777216 (overlays dead x_bf)
  u16* wqkv_t = (u16*)(ws + 25165824);   // [8192][3072] = 50331648 (q|k|v transposed, contiguous)
  u16* kw_t   = (u16*)(ws + 50331648);   // = wqkv_t + 4096 rows
  u16* vw_t   = (u16*)(ws + 62914560);   // = wqkv_t + 6144 rows
  u16* ow_t   = (u16*)(ws + 75497472);   // [3072][4096] = 25165824
  u16* xqkv   = (u16*)(ws + 100663296);  // [4096][8192] = 67108864 -> end 167772160
  u16* attn   = (u16*)(ws + 25165824);   // overlays dead wqkv_t after QKV GEMM (33.5MB <= 50.3MB)

  cast_f32_bf16<<<12288, 256, 0, stream>>>(hs, x_bf, 4096 * 3072 / 4);
  transpose_cast<<<dim3(64, 48), 256, 0, stream>>>(qw, wqkv_t, 3072, 4096);
  transpose_cast<<<dim3(32, 48), 256, 0, stream>>>(kw, kw_t, 3072, 2048);
  transpose_cast<<<dim3(32, 48), 256, 0, stream>>>(vw, vw_t, 3072, 2048);
  transpose_cast<<<dim3(48, 64), 256, 0, stream>>>(ow, ow_t, 4096, 3072);

  // merged QKV projection: [4096][3072] x [8192][3072]^T -> [4096][8192]
  gemm256<false><<<dim3(32, 16), 512, 0, stream>>>(x_bf, wqkv_t, xqkv, 4096, 8192, 3072);

  rmsnorm_rope<<<dim3(4096, 4), 256, 0, stream>>>(xqkv, qnw, fc, fsn, 16, QKS_, SCALE_);
  rmsnorm_rope<<<dim3(4096, 2), 256, 0, stream>>>(xqkv + 4096, knw, fc, fsn, 8, QKS_, 1.0f);

  transpose_v<<<dim3(32, 64), 256, 0, stream>>>(xqkv + 6144, vt);

  flash_attn<<<dim3(16, 16, 2), 256, 0, stream>>>(xqkv, xqkv + 4096, vt, attn);

  gemm256<true><<<dim3(12, 16), 512, 0, stream>>>(attn, ow_t, (float*)d_out, 4096, 3072, 4096);
}

// Round 10
// 788.056 us; speedup vs baseline: 1.1530x; 1.1530x over previous
//
#include <hip/hip_runtime.h>
#include <hip/hip_bf16.h>
#include <cstdint>

#define B_   2
#define S_   2048
#define HID_ 3072
#define H_   16
#define KV_  8
#define D_   256
#define HD_  4096   // H_*D_
#define KVD_ 2048   // KV_*D_
#define QKS_ 8192   // merged qkv row stride

constexpr float EPS_   = 1e-6f;
constexpr float SCALE_ = 0.0625f;   // 256^-0.5

typedef unsigned short u16;
typedef __attribute__((ext_vector_type(8))) short bf16x8;
typedef __attribute__((ext_vector_type(4))) float f32x4;

__device__ inline float bf2f(u16 u) { return __uint_as_float(((unsigned int)u) << 16); }
__device__ inline u16 f2bf(float f) {
  unsigned int x = __float_as_uint(f);
  x += 0x7fffu + ((x >> 16) & 1u);   // RNE
  return (u16)(x >> 16);
}

// async global->LDS, 16B per lane; lds base must be wave-uniform, data lands at base + lane*16
__device__ inline void gll16(const u16* g, u16* l) {
  __builtin_amdgcn_global_load_lds((const __attribute__((address_space(1))) unsigned int*)g,
                                   (__attribute__((address_space(3))) unsigned int*)l,
                                   16, 0, 0);
}

// ---------------- elementwise cast f32 -> bf16 (n4 = n/4) ----------------
__global__ void cast_f32_bf16(const float* __restrict__ in, u16* __restrict__ out, int n4) {
  int i = blockIdx.x * blockDim.x + threadIdx.x;
  if (i < n4) {
    float4 v = ((const float4*)in)[i];
    ushort4 o;
    o.x = f2bf(v.x); o.y = f2bf(v.y); o.z = f2bf(v.z); o.w = f2bf(v.w);
    ((ushort4*)out)[i] = o;
  }
}

// ------------- transpose+cast: in[K][N] f32 -> out[N][K] bf16 -------------
__global__ void transpose_cast(const float* __restrict__ in, u16* __restrict__ out, int K, int N) {
  __shared__ __align__(16) float tile[64][65];
  int n0 = blockIdx.x * 64, k0 = blockIdx.y * 64;
  int t = threadIdx.x;
  int rr = t >> 4, cc = (t & 15) * 4;
  for (int i = 0; i < 4; i++) {
    float4 v = *(const float4*)(&in[(size_t)(k0 + rr + 16 * i) * N + n0 + cc]);
    tile[rr + 16 * i][cc + 0] = v.x; tile[rr + 16 * i][cc + 1] = v.y;
    tile[rr + 16 * i][cc + 2] = v.z; tile[rr + 16 * i][cc + 3] = v.w;
  }
  __syncthreads();
  for (int i = 0; i < 4; i++) {
    int orow = rr + 16 * i;  // n index
    ushort4 o;
    o.x = f2bf(tile[cc + 0][orow]); o.y = f2bf(tile[cc + 1][orow]);
    o.z = f2bf(tile[cc + 2][orow]); o.w = f2bf(tile[cc + 3][orow]);
    *(ushort4*)(&out[(size_t)(n0 + orow) * K + k0 + cc]) = o;
  }
}

// ----- bf16 transpose: in (xqkv V cols, stride 8192) -> out[b][2048 n][2048 s] -----
__global__ void transpose_v(const u16* __restrict__ in, u16* __restrict__ out) {
  __shared__ __align__(16) u16 tile[64][68];
  int n0 = blockIdx.x * 64, tk0 = blockIdx.y * 64;
  int b = tk0 >> 11, s0 = tk0 & (S_ - 1);
  int t = threadIdx.x;
  int rr = t >> 4, cc = (t & 15) * 4;
  for (int i = 0; i < 4; i++) {
    ushort4 v = *(const ushort4*)(&in[(size_t)(tk0 + rr + 16 * i) * QKS_ + n0 + cc]);
    tile[rr + 16 * i][cc + 0] = v.x; tile[rr + 16 * i][cc + 1] = v.y;
    tile[rr + 16 * i][cc + 2] = v.z; tile[rr + 16 * i][cc + 3] = v.w;
  }
  __syncthreads();
  for (int i = 0; i < 4; i++) {
    int orow = rr + 16 * i;  // n index
    ushort4 o;
    o.x = tile[cc + 0][orow]; o.y = tile[cc + 1][orow];
    o.z = tile[cc + 2][orow]; o.w = tile[cc + 3][orow];
    *(ushort4*)(&out[((size_t)b << 22) + (size_t)(n0 + orow) * S_ + s0 + cc]) = o;
  }
}

// ===== 256x256 8-wave GEMM, m201-faithful 8-phase/2-tile schedule =====
// v7 = v6 with the staging-visibility race fixed: the cross-buffer pre-reads
// (P4's B01' from buf1, P8's B01 from buf0) are issued AFTER the phase's
// first barrier (which follows every wave's vmcnt) — vmcnt is per-wave, so a
// pre-barrier read could observe other waves' stages before they landed
// (round-9 absmax 0.203). Reads placed after the MFMA cluster so MFMA start
// is not delayed; they are lgkm-waited by the next phase's lgkmcnt(0).
// Schedule otherwise identical to v6 (see round-8 comment for phase map and
// FIFO-derived vmcnt accounting; steady-state invariant: entering each pair,
// outstanding = [Ah0,Ah1(2u+1)] = 4).
template <bool OUTF32>
__global__ __launch_bounds__(512, 2) void gemm256(const u16* __restrict__ A,
                                                  const u16* __restrict__ Bt,
                                                  void* __restrict__ Cv, int M, int N, int K) {
  __shared__ __align__(16) u16 As[2][16384];
  __shared__ __align__(16) u16 Bs[2][16384];
  int t = threadIdx.x, lane = t & 63, wave = t >> 6;
  int quad = lane >> 4, l16 = lane & 15;
  int wm = wave >> 2, wn = wave & 3;

  // XCD-chunked bid swizzle (requires nwg % 8 == 0; 512 and 192 both qualify)
  int nwg = gridDim.x * gridDim.y;
  int bid = blockIdx.y * gridDim.x + blockIdx.x;
  int sbid = (bid & 7) * (nwg >> 3) + (bid >> 3);
  int bn = (sbid % gridDim.x) * 256;
  int bm = (sbid / gridDim.x) * 256;

  // staging: one gll16 fills one 16x32 subtile (1KB); lane l -> row l>>2,
  // phys slot l&3 holding logical slot (l&3)^((l>>3)&3)
  int srow = lane >> 2;
  int scol8 = ((lane & 3) ^ ((lane >> 3) & 3)) * 8;
  const u16* ap = A + (size_t)(bm + srow) * K + scol8;
  const u16* bp = Bt + (size_t)(bn + srow) * K + scol8;

  auto stA = [&](int sr, int sc, int k0, int bufi) {
    gll16(ap + (size_t)(sr * 16) * K + k0 + sc * 32, &As[bufi][(sr * 2 + sc) * 512]);
  };
  auto stB = [&](int sr, int sc, int k0, int bufi) {
    gll16(bp + (size_t)(sr * 16) * K + k0 + sc * 32, &Bs[bufi][(sr * 2 + sc) * 512]);
  };
  auto stAh = [&](int h, int kt, int bufi) {   // one A half-tile = 2 gll16/wave
    stA(h * 8 + wave, 0, kt * 64, bufi);
    stA(h * 8 + wave, 1, kt * 64, bufi);
  };
  auto stBh = [&](int h, int kt, int bufi) {   // one B half-tile = 2 gll16/wave
    stB(h * 8 + wave, 0, kt * 64, bufi);
    stB(h * 8 + wave, 1, kt * 64, bufi);
  };

  // frag read offset within a subtile (uniform banks: slot = quad ^ ((l16>>1)&3))
  int rsw = l16 * 32 + ((quad ^ ((l16 >> 1) & 3)) * 8);
  auto LDA = [&](int bufi, int i, int ks) {
    return *(const bf16x8*)(&As[bufi][((wm * 8 + i) * 2 + ks) * 512 + rsw]);
  };
  auto LDB = [&](int bufi, int j, int ks) {
    return *(const bf16x8*)(&Bs[bufi][((wn * 4 + j) * 2 + ks) * 512 + rsw]);
  };

  f32x4 acc[8][4] = {};
  bf16x8 A0[4][2], A1[4][2], B01[2][2], B23[2][2];
  int NT = K >> 6, NP = NT >> 1;

  // prologue: stage A(0),B(0),A(1); retire A(0),B(0) [leaves A(1)=4 in flight,
  // the steady-state entering invariant]; pre-read B01(tile 0, buf0) — safe:
  // after vmcnt+barrier.
  stAh(0, 0, 0); stAh(1, 0, 0);
  stBh(0, 0, 0); stBh(1, 0, 0);
  stAh(0, 1, 1); stAh(1, 1, 1);
  asm volatile("s_waitcnt vmcnt(4)" ::: "memory");
  __builtin_amdgcn_s_barrier();
  asm volatile("" ::: "memory");
#pragma unroll
  for (int j = 0; j < 2; j++) { B01[j][0] = LDB(0, j, 0); B01[j][1] = LDB(0, j, 1); }

#define MFMA_CL(IOFS, JOFS, AA, BB)                                            \
  __builtin_amdgcn_s_setprio(1);                                               \
  _Pragma("unroll")                                                            \
  for (int i_ = 0; i_ < 4; i_++)                                               \
    _Pragma("unroll")                                                          \
    for (int j_ = 0; j_ < 2; j_++) {                                           \
      acc[i_ + IOFS][j_ + JOFS] = __builtin_amdgcn_mfma_f32_16x16x32_bf16(     \
          AA[i_][0], BB[j_][0], acc[i_ + IOFS][j_ + JOFS], 0, 0, 0);           \
      acc[i_ + IOFS][j_ + JOFS] = __builtin_amdgcn_mfma_f32_16x16x32_bf16(     \
          AA[i_][1], BB[j_][1], acc[i_ + IOFS][j_ + JOFS], 0, 0, 0);           \
    }                                                                          \
  __builtin_amdgcn_s_setprio(0);

#define PH_TAIL(IOFS, JOFS, AA, BB)                                            \
  __builtin_amdgcn_s_barrier();                                                \
  asm volatile("s_waitcnt lgkmcnt(0)" ::: "memory");                           \
  MFMA_CL(IOFS, JOFS, AA, BB)                                                  \
  __builtin_amdgcn_s_barrier();                                                \
  asm volatile("" ::: "memory");

#pragma unroll 1
  for (int u = 0; u < NP; u++) {
    bool sL = (u + 1) < NP;          // stages for tiles 2u+2 / 2u+3 exist
    int k2 = 2 * u + 2, k3 = 2 * u + 3;

    // ---- P1 (tile 2u, buf0): read A0; stage B(2u+1)h0->buf1; MFMA (m0,n01) ----
#pragma unroll
    for (int i = 0; i < 4; i++) { A0[i][0] = LDA(0, i, 0); A0[i][1] = LDA(0, i, 1); }
    stBh(0, 2 * u + 1, 1);
    PH_TAIL(0, 0, A0, B01)
    // ---- P2: read A1; stage B(2u+1)h1; MFMA (m1,n01); B01 dead ----
#pragma unroll
    for (int i = 0; i < 4; i++) { A1[i][0] = LDA(0, i + 4, 0); A1[i][1] = LDA(0, i + 4, 1); }
    stBh(1, 2 * u + 1, 1);
    PH_TAIL(4, 0, A1, B01)
    // ---- P3: read B23; stage A(2u+2)h0->buf0 (A buf0 reads retired @P2); MFMA (m0,n23) ----
#pragma unroll
    for (int j = 0; j < 2; j++) { B23[j][0] = LDB(0, j + 2, 0); B23[j][1] = LDB(0, j + 2, 1); }
    if (sL) stAh(0, k2, 0);
    PH_TAIL(0, 2, A0, B23)
    // ---- P4: vmcnt retires A(2u+1)+B(2u+1); stage A(2u+2)h1; barrier;
    //          MFMA (m1,n23); THEN read B01'(buf1, tile 2u+1) — safe: after
    //          barrier-after-vmcnt, all waves' B(2u+1) stages landed ----
    if (sL) asm volatile("s_waitcnt vmcnt(2)" ::: "memory");
    else    asm volatile("s_waitcnt vmcnt(0)" ::: "memory");
    if (sL) stAh(1, k2, 0);
    __builtin_amdgcn_s_barrier();
    asm volatile("s_waitcnt lgkmcnt(0)" ::: "memory");
    MFMA_CL(4, 2, A1, B23)
#pragma unroll
    for (int j = 0; j < 2; j++) { B01[j][0] = LDB(1, j, 0); B01[j][1] = LDB(1, j, 1); }
    __builtin_amdgcn_s_barrier();
    asm volatile("" ::: "memory");
    // ---- P5 (tile 2u+1, buf1): read A0; stage B(2u+2)h0->buf0 (B buf0 reads retired @P3) ----
#pragma unroll
    for (int i = 0; i < 4; i++) { A0[i][0] = LDA(1, i, 0); A0[i][1] = LDA(1, i, 1); }
    if (sL) stBh(0, k2, 0);
    PH_TAIL(0, 0, A0, B01)
    // ---- P6: read A1; stage B(2u+2)h1; MFMA (m1,n01) ----
#pragma unroll
    for (int i = 0; i < 4; i++) { A1[i][0] = LDA(1, i + 4, 0); A1[i][1] = LDA(1, i + 4, 1); }
    if (sL) stBh(1, k2, 0);
    PH_TAIL(4, 0, A1, B01)
    // ---- P7: read B23; stage A(2u+3)h0->buf1 (A buf1 reads retired @P6); MFMA (m0,n23) ----
#pragma unroll
    for (int j = 0; j < 2; j++) { B23[j][0] = LDB(1, j + 2, 0); B23[j][1] = LDB(1, j + 2, 1); }
    if (sL) stAh(0, k3, 1);
    PH_TAIL(0, 2, A0, B23)
    // ---- P8: vmcnt retires A(2u+2)+B(2u+2); stage A(2u+3)h1; barrier;
    //          MFMA (m1,n23); THEN read B01(next pair, buf0) — safe as P4 ----
    if (sL) asm volatile("s_waitcnt vmcnt(2)" ::: "memory");
    else    asm volatile("s_waitcnt vmcnt(0)" ::: "memory");
    if (sL) stAh(1, k3, 1);
    __builtin_amdgcn_s_barrier();
    asm volatile("s_waitcnt lgkmcnt(0)" ::: "memory");
    MFMA_CL(4, 2, A1, B23)
    if (sL) {
#pragma unroll
      for (int j = 0; j < 2; j++) { B01[j][0] = LDB(0, j, 0); B01[j][1] = LDB(0, j, 1); }
    }
    __builtin_amdgcn_s_barrier();
    asm volatile("" ::: "memory");
  }
#undef PH_TAIL
#undef MFMA_CL

  // epilogue
#pragma unroll
  for (int i = 0; i < 8; i++)
#pragma unroll
    for (int j = 0; j < 4; j++)
#pragma unroll
      for (int r = 0; r < 4; r++) {
        int row = bm + wm * 128 + i * 16 + quad * 4 + r;
        int col = bn + wn * 64 + j * 16 + l16;
        float v = acc[i][j][r];
        if (OUTF32) ((float*)Cv)[(size_t)row * N + col] = v;
        else ((u16*)Cv)[(size_t)row * N + col] = f2bf(v);
      }
}

// ----- fused RMSNorm + RoPE, in place on bf16 [token][stride]; 1 wave/head -----
__global__ void rmsnorm_rope(u16* __restrict__ x, const float* __restrict__ w,
                             const float* __restrict__ fc, const float* __restrict__ fsn,
                             int nh, int stride, float outscale) {
  int token = blockIdx.x;
  int head = blockIdx.y * 4 + (threadIdx.x >> 6);
  if (head >= nh) return;
  int lane = threadIdx.x & 63;
  int s = token & (S_ - 1);
  u16* p = x + (size_t)token * stride + head * D_;
  float v0 = bf2f(p[lane]);
  float v1 = bf2f(p[lane + 64]);
  float v2 = bf2f(p[lane + 128]);
  float v3 = bf2f(p[lane + 192]);
  float ss = v0 * v0 + v1 * v1 + v2 * v2 + v3 * v3;
  for (int off = 32; off; off >>= 1) ss += __shfl_xor(ss, off, 64);
  float rs = rsqrtf(ss * (1.0f / D_) + EPS_);
  float n0 = v0 * rs * (1.0f + w[lane]);
  float n1 = v1 * rs * (1.0f + w[lane + 64]);
  float n2 = v2 * rs * (1.0f + w[lane + 128]);
  float n3 = v3 * rs * (1.0f + w[lane + 192]);
  float c0 = fc[s * 128 + lane], s0 = fsn[s * 128 + lane];
  float c1 = fc[s * 128 + lane + 64], s1 = fsn[s * 128 + lane + 64];
  p[lane]       = f2bf((n0 * c0 - n2 * s0) * outscale);
  p[lane + 128] = f2bf((n0 * s0 + n2 * c0) * outscale);
  p[lane + 64]  = f2bf((n1 * c1 - n3 * s1) * outscale);
  p[lane + 192] = f2bf((n1 * s1 + n3 * c1) * outscale);
}

// ---------------- flash attention, causal, GQA rep=2, D=256 ----------------
// v4 + merged-qkv strides: Q/K rows have stride 8192.
__global__ __launch_bounds__(256, 3) void flash_attn(const u16* __restrict__ Q,
                                                     const u16* __restrict__ Kb,
                                                     const u16* __restrict__ Vt,
                                                     u16* __restrict__ O) {
  __shared__ __align__(16) u16 Ks[2][8 * 1024];   // [buf][chunk c][key 0..31][slot-swz 32 d]
  __shared__ __align__(16) u16 Vs[8 * 1024];      // [d 0..255][slot-swz 32 k]
  int t = threadIdx.x, lane = t & 63, wave = t >> 6;
  int quad = lane >> 4, l16 = lane & 15;
  int h = blockIdx.y, b = blockIdx.z;
  int kvh = h >> 1;

  int swz = ((lane & 3) ^ ((lane >> 2) & 3)) * 8;        // staging-side d/k offset
  int rswz = (quad ^ (l16 & 3)) * 8;                     // read-side slot offset
  const u16* kst = Kb + (size_t)(b * S_ + (lane >> 2)) * QKS_ + kvh * D_ + wave * 64 + swz;
  const u16* vst = Vt + ((size_t)b << 22) + (size_t)(kvh * D_ + wave * 64 + (lane >> 2)) * S_ + swz;

  auto stageK = [&](int kt, int bufi) {
    u16* kdst = &Ks[bufi][wave * 2048];
    const u16* ksrc = kst + (size_t)(kt * 32) * QKS_;
#pragma unroll
    for (int c2 = 0; c2 < 2; c2++)
#pragma unroll
      for (int r = 0; r < 2; r++)
        gll16(ksrc + (size_t)(r * 16) * QKS_ + c2 * 32, kdst + c2 * 1024 + r * 512);
  };  // 4 gll16
  auto stageV = [&](int kt) {
    u16* vdst = &Vs[wave * 2048];
#pragma unroll
    for (int c = 0; c < 4; c++)
      gll16(vst + (size_t)(c * 16) * S_ + kt * 32, vdst + c * 512);
  };  // 4 gll16

#pragma unroll 1
  for (int half = 0; half < 2; half++) {
    // big q-tile first, then the paired small one: iters (64-2bx) + (2bx+2) = 66
    int qb = (half == 0) ? (31 - (int)blockIdx.x) * 64 : (int)blockIdx.x * 64;
    int qw = qb + wave * 16;

    bf16x8 qf[8];
    const u16* qp = Q + ((size_t)(b * S_) + qw + l16) * QKS_ + h * D_;
#pragma unroll
    for (int c = 0; c < 8; c++) qf[c] = *(const bf16x8*)(qp + c * 32 + quad * 8);

    f32x4 o_acc[16] = {};
    float m_s = -3e38f, l_s = 0.f;    // per-lane softmax state for row q = qw + l16

    int nkt = (qb + 64) >> 5;
    stageK(0, 0);
    stageV(0);
#pragma unroll 1
    for (int kt = 0; kt < nkt; kt++) {
      int cur = kt & 1;
      asm volatile("s_waitcnt vmcnt(4)" ::: "memory");
      __builtin_amdgcn_s_barrier();
      asm volatile("" ::: "memory");
      if (kt + 1 < nkt) stageK(kt + 1, cur ^ 1);

      // ---- QK (swapped): sc[key][q], q = l16 ----
      f32x4 sc0 = {}, sc1 = {};
#pragma unroll
      for (int c = 0; c < 8; c++) {
        bf16x8 k0 = *(const bf16x8*)(&Ks[cur][c * 1024 + l16 * 32 + rswz]);
        bf16x8 k1 = *(const bf16x8*)(&Ks[cur][c * 1024 + (l16 + 16) * 32 + rswz]);
        sc0 = __builtin_amdgcn_mfma_f32_16x16x32_bf16(k0, qf[c], sc0, 0, 0, 0);
        sc1 = __builtin_amdgcn_mfma_f32_16x16x32_bf16(k1, qf[c], sc1, 0, 0, 0);
      }

      // ---- lane-local online softmax (row q = qw + l16) ----
      int qg = qw + l16;
      int kbase = kt * 32 + quad * 4;
      float p0[4], p1[4];
      float mx = -1e30f;
#pragma unroll
      for (int r = 0; r < 4; r++) {
        p0[r] = (kbase + r <= qg) ? sc0[r] : -1e30f;
        p1[r] = (kbase + 16 + r <= qg) ? sc1[r] : -1e30f;
        mx = fmaxf(mx, fmaxf(p0[r], p1[r]));
      }
      mx = fmaxf(mx, __shfl_xor(mx, 16));
      mx = fmaxf(mx, __shfl_xor(mx, 32));
      float mn = fmaxf(m_s, mx);
      bool chg = mn > m_s;
      float rsum = 0.f;
#pragma unroll
      for (int r = 0; r < 4; r++) {
        p0[r] = __expf(p0[r] - mn);
        p1[r] = __expf(p1[r] - mn);
        rsum += p0[r] + p1[r];
      }
      if (__any((int)chg)) {
        float alpha = __expf(m_s - mn);
        float ar[4];
#pragma unroll
        for (int r = 0; r < 4; r++) ar[r] = __shfl(alpha, quad * 20 + r);
#pragma unroll
        for (int nt = 0; nt < 16; nt++)
#pragma unroll
          for (int r = 0; r < 4; r++) o_acc[nt][r] *= ar[r];
        l_s *= alpha;
      }
      m_s = mn;
      rsum += __shfl_xor(rsum, 16);
      rsum += __shfl_xor(rsum, 32);
      l_s += rsum;

      // ---- P: C-layout -> A-frag fully in-register (2-stage butterfly) ----
      unsigned int w_[4], x_[4], gl[4], gh[4], sn[4], rc[4];
      w_[0] = (unsigned)f2bf(p0[0]) | ((unsigned)f2bf(p0[1]) << 16);
      w_[1] = (unsigned)f2bf(p0[2]) | ((unsigned)f2bf(p0[3]) << 16);
      w_[2] = (unsigned)f2bf(p1[0]) | ((unsigned)f2bf(p1[1]) << 16);
      w_[3] = (unsigned)f2bf(p1[2]) | ((unsigned)f2bf(p1[3]) << 16);
#pragma unroll
      for (int i = 0; i < 4; i++) x_[i] = (unsigned)__shfl_xor((int)w_[i], 16);
      bool odd = (quad & 1) != 0;
      gl[0] = odd ? x_[0] : w_[0]; gl[1] = odd ? x_[1] : w_[1];
      gl[2] = odd ? w_[0] : x_[0]; gl[3] = odd ? w_[1] : x_[1];
      gh[0] = odd ? x_[2] : w_[2]; gh[1] = odd ? x_[3] : w_[3];
      gh[2] = odd ? w_[2] : x_[2]; gh[3] = odd ? w_[3] : x_[3];
#pragma unroll
      for (int i = 0; i < 4; i++) sn[i] = odd ? gl[i] : gh[i];
#pragma unroll
      for (int i = 0; i < 4; i++) rc[i] = (unsigned)__shfl_xor((int)sn[i], 32);
      union { unsigned int u[4]; bf16x8 v; } pfc;
#pragma unroll
      for (int i = 0; i < 4; i++)
        pfc.u[i] = (quad == 0) ? gl[i] : (quad == 3) ? gh[i] : rc[i];
      bf16x8 pf = pfc.v;

      if (kt + 1 < nkt) asm volatile("s_waitcnt vmcnt(4)" ::: "memory");
      else              asm volatile("s_waitcnt vmcnt(0)" ::: "memory");
      __builtin_amdgcn_s_barrier();
      asm volatile("" ::: "memory");

      // ---- PV ----
#pragma unroll
      for (int nt = 0; nt < 16; nt++) {
        bf16x8 vf = *(const bf16x8*)(&Vs[(nt * 16 + l16) * 32 + rswz]);
        o_acc[nt] = __builtin_amdgcn_mfma_f32_16x16x32_bf16(pf, vf, o_acc[nt], 0, 0, 0);
      }

      asm volatile("s_waitcnt lgkmcnt(0)" ::: "memory");
      __builtin_amdgcn_s_barrier();
      asm volatile("" ::: "memory");
      if (kt + 1 < nkt) stageV(kt + 1);
    }

    float invl = 1.0f / l_s;
    float inv_r[4];
#pragma unroll
    for (int r = 0; r < 4; r++) inv_r[r] = __shfl(invl, quad * 20 + r);
    for (int r = 0; r < 4; r++) {
      int qg2 = qw + quad * 4 + r;
      u16* op = O + ((size_t)(b * S_) + qg2) * HD_ + h * D_;
      for (int nt = 0; nt < 16; nt++) op[nt * 16 + l16] = f2bf(o_acc[nt][r] * inv_r[r]);
    }
  }
}

extern "C" void kernel_launch(void* const* d_in, const int* in_sizes, int n_in,
                              void* d_out, int out_size, void* d_ws, size_t ws_size,
                              hipStream_t stream) {
  const float* hs  = (const float*)d_in[0];
  const float* fc  = (const float*)d_in[1];
  const float* fsn = (const float*)d_in[2];
  // d_in[3] = mask: causal, replicated analytically
  const float* qw  = (const float*)d_in[4];
  const float* kw  = (const float*)d_in[5];
  const float* vw  = (const float*)d_in[6];
  const float* ow  = (const float*)d_in[7];
  const float* qnw = (const float*)d_in[8];
  const float* knw = (const float*)d_in[9];

  char* ws = (char*)d_ws;
  // layout (bytes):
  u16* x_bf   = (u16*)(ws + 0);          // 4096*3072*2 = 25165824 (dead after QKV GEMM)
  u16* vt     = (u16*)(ws + 0);          // 2*2048*2048*2 = 16777216 (overlays dead x_bf)
  u16* wqkv_t = (u16*)(ws + 25165824);   // [8192][3072] = 50331648 (q|k|v transposed, contiguous)
  u16* kw_t   = (u16*)(ws + 50331648);   // = wqkv_t + 4096 rows
  u16* vw_t   = (u16*)(ws + 62914560);   // = wqkv_t + 6144 rows
  u16* ow_t   = (u16*)(ws + 75497472);   // [3072][4096] = 25165824
  u16* xqkv   = (u16*)(ws + 100663296);  // [4096][8192] = 67108864 -> end 167772160
  u16* attn   = (u16*)(ws + 25165824);   // overlays dead wqkv_t after QKV GEMM (33.5MB <= 50.3MB)

  cast_f32_bf16<<<12288, 256, 0, stream>>>(hs, x_bf, 4096 * 3072 / 4);
  transpose_cast<<<dim3(64, 48), 256, 0, stream>>>(qw, wqkv_t, 3072, 4096);
  transpose_cast<<<dim3(32, 48), 256, 0, stream>>>(kw, kw_t, 3072, 2048);
  transpose_cast<<<dim3(32, 48), 256, 0, stream>>>(vw, vw_t, 3072, 2048);
  transpose_cast<<<dim3(48, 64), 256, 0, stream>>>(ow, ow_t, 4096, 3072);

  // merged QKV projection: [4096][3072] x [8192][3072]^T -> [4096][8192]
  gemm256<false><<<dim3(32, 16), 512, 0, stream>>>(x_bf, wqkv_t, xqkv, 4096, 8192, 3072);

  rmsnorm_rope<<<dim3(4096, 4), 256, 0, stream>>>(xqkv, qnw, fc, fsn, 16, QKS_, SCALE_);
  rmsnorm_rope<<<dim3(4096, 2), 256, 0, stream>>>(xqkv + 4096, knw, fc, fsn, 8, QKS_, 1.0f);

  transpose_v<<<dim3(32, 64), 256, 0, stream>>>(xqkv + 6144, vt);

  flash_attn<<<dim3(16, 16, 2), 256, 0, stream>>>(xqkv, xqkv + 4096, vt, attn);

  gemm256<true><<<dim3(12, 16), 512, 0, stream>>>(attn, ow_t, (float*)d_out, 4096, 3072, 4096);
}